// Round 2
// baseline (202.775 us; speedup 1.0000x reference)
//
#include <hip/hip_runtime.h>

// Bidirectional NN (Chamfer-style) L1 loss on 2-D points.
//   preds: (B=64, N=2048, F=4) fp32, targs: (B=64, M=2048, F=4) fp32,
//   subcoef: (D=2,) fp32. Distance over features [0:2) only.
// Key trick: argmin_m (p-t_m)^2 == argmin_m (|t_m|^2 - 2 p.t_m)  (|p|^2 const).
// Inner loop per point-candidate: 2 FMA + cmp + 2 cndmask (~5.5 VALU amortized).
constexpr int B = 64;
constexpr int N = 2048;
constexpr int M = 2048;
constexpr int F = 4;
constexpr int BLOCK = 256;
constexpr int P = 4;   // source points per thread: amortizes LDS + candidate norm

__global__ void __launch_bounds__(BLOCK)
nnloss_kernel(const float* __restrict__ preds,
              const float* __restrict__ targs,
              const float* __restrict__ subcoef,
              float* __restrict__ out) {
    __shared__ float2 sdst[M];          // 16 KB: this batch's candidate points
    __shared__ float  wsum[BLOCK / 64];

    const int dir = blockIdx.z;         // 0: preds->targs (subcoef), 1: targs->preds
    const int b   = blockIdx.y;
    const int tid = threadIdx.x;

    const float* src = dir ? targs : preds;
    const float* dst = dir ? preds : targs;

    // Stage candidates (x,y) into LDS. (b*M+i)*F floats = 16B-aligned.
    const float* dstb = dst + (size_t)b * M * F;
    for (int i = tid; i < M; i += BLOCK) {
        sdst[i] = *reinterpret_cast<const float2*>(dstb + (size_t)i * F);
    }
    __syncthreads();

    // Each thread owns P source points (stride BLOCK for coalescing).
    const int base = blockIdx.x * (BLOCK * P);
    float px[P], py[P], n2x[P], n2y[P], bd[P];
    int   bm[P];
    #pragma unroll
    for (int j = 0; j < P; ++j) {
        const int n = base + j * BLOCK + tid;
        const float2 p = *reinterpret_cast<const float2*>(src + ((size_t)b * N + n) * F);
        px[j] = p.x;  py[j] = p.y;
        n2x[j] = -2.0f * p.x;
        n2y[j] = -2.0f * p.y;
        bd[j] = 3.4028235e38f;
        bm[j] = 0;
    }

    // Scan all candidates, 2 per ds_read_b128.
    const float4* sdst4 = reinterpret_cast<const float4*>(sdst);
    #pragma unroll 8
    for (int mp = 0; mp < M / 2; ++mp) {
        const float4 tt = sdst4[mp];                 // cand a=(x,y), b=(z,w)
        const float na = fmaf(tt.y, tt.y, tt.x * tt.x);   // |t_a|^2
        const float nb = fmaf(tt.w, tt.w, tt.z * tt.z);   // |t_b|^2
        const int ma = 2 * mp, mb = 2 * mp + 1;
        #pragma unroll
        for (int j = 0; j < P; ++j) {
            // d2' = |t|^2 - 2 p.t ; strict < keeps FIRST minimal index.
            const float da = fmaf(n2y[j], tt.y, fmaf(n2x[j], tt.x, na));
            if (da < bd[j]) { bd[j] = da; bm[j] = ma; }
            const float db = fmaf(n2y[j], tt.w, fmaf(n2x[j], tt.z, nb));
            if (db < bd[j]) { bd[j] = db; bm[j] = mb; }
        }
    }

    // L1 contribution against the winning candidate.
    float c0 = 1.0f, c1 = 1.0f;
    if (dir == 0) { c0 = subcoef[0]; c1 = subcoef[1]; }
    float acc = 0.0f;
    #pragma unroll
    for (int j = 0; j < P; ++j) {
        const float2 q = sdst[bm[j]];   // one divergent gather per point
        acc += fabsf(px[j] - q.x) * c0 + fabsf(py[j] - q.y) * c1;
    }

    // Wave (64) shuffle reduction -> block reduction -> one atomic per block.
    #pragma unroll
    for (int off = 32; off > 0; off >>= 1) acc += __shfl_down(acc, off, 64);
    if ((tid & 63) == 0) wsum[tid >> 6] = acc;
    __syncthreads();
    if (tid == 0) {
        float s = 0.0f;
        #pragma unroll
        for (int w = 0; w < BLOCK / 64; ++w) s += wsum[w];
        atomicAdd(out, s);
    }
}

extern "C" void kernel_launch(void* const* d_in, const int* in_sizes, int n_in,
                              void* d_out, int out_size, void* d_ws, size_t ws_size,
                              hipStream_t stream) {
    const float* preds   = (const float*)d_in[0];
    const float* targs   = (const float*)d_in[1];
    const float* subcoef = (const float*)d_in[2];
    float* out = (float*)d_out;

    hipMemsetAsync(out, 0, sizeof(float), stream);

    // 2 x 64 x 2 = 256 blocks = 1 per CU; 4 waves/block.
    dim3 grid(N / (BLOCK * P), B, 2);
    nnloss_kernel<<<grid, BLOCK, 0, stream>>>(preds, targs, subcoef, out);
}

// Round 3
// 145.545 us; speedup vs baseline: 1.3932x; 1.3932x over previous
//
#include <hip/hip_runtime.h>

// Bidirectional NN (Chamfer-style) L1 loss on 2-D points.
//   preds: (B=64, N=2048, F=4) fp32, targs: (B=64, M=2048, F=4) fp32,
//   subcoef: (D=2,) fp32. Distance over features [0:2) only.
// argmin_m (p-t_m)^2 == argmin_m (|t_m|^2 - 2 p.t_m)   (|p|^2 per-query const).
// LDS layout per candidate PAIR mp: [x_{2mp}, x_{2mp+1}, y_{2mp}, y_{2mp+1}]
// -> one ds_read_b128 yields X01=(x0,x1), Y01=(y0,y1) as packed-f32 reg pairs,
//    distances for 2 candidates = 2 v_pk_fma_f32 per point.
constexpr int B = 64;
constexpr int N = 2048;
constexpr int M = 2048;
constexpr int F = 4;
constexpr int BLOCK = 256;
constexpr int P = 2;   // points per thread (total waves = 4096/P -> 2/SIMD)

typedef float v2f __attribute__((ext_vector_type(2)));

__global__ void __launch_bounds__(BLOCK)
nnloss_kernel(const float* __restrict__ preds,
              const float* __restrict__ targs,
              const float* __restrict__ subcoef,
              float* __restrict__ out) {
    __shared__ float sc[M * 2];          // 16 KB, pair-interleaved (see header)
    __shared__ float wsum[BLOCK / 64];

    const int dir = blockIdx.z;          // 0: preds->targs (subcoef), 1: reverse
    const int b   = blockIdx.y;
    const int tid = threadIdx.x;

    const float* src = dir ? targs : preds;
    const float* dst = dir ? preds : targs;

    // Stage candidates into pair-interleaved LDS.
    const float* dstb = dst + (size_t)b * M * F;
    for (int i = tid; i < M; i += BLOCK) {
        const float2 c = *reinterpret_cast<const float2*>(dstb + (size_t)i * F);
        const int g = i >> 1, o = i & 1;
        sc[g * 4 + o]     = c.x;
        sc[g * 4 + 2 + o] = c.y;
    }
    __syncthreads();

    // Each thread owns P points (stride BLOCK for coalescing).
    const int base = blockIdx.x * (BLOCK * P);
    float px[P], py[P], bd[P];
    v2f   n2x[P], n2y[P];
    int   bm[P];
    #pragma unroll
    for (int j = 0; j < P; ++j) {
        const int n = base + j * BLOCK + tid;
        const float2 p = *reinterpret_cast<const float2*>(src + ((size_t)b * N + n) * F);
        px[j] = p.x;  py[j] = p.y;
        const float ax = -2.0f * p.x, ay = -2.0f * p.y;
        n2x[j] = (v2f){ax, ax};          // splats live in regs; VOP3P sources
        n2y[j] = (v2f){ay, ay};
        bd[j] = 3.4028235e38f;
        bm[j] = 0;
    }

    const float4* sc4 = reinterpret_cast<const float4*>(sc);
    #pragma unroll 4
    for (int mp = 0; mp < M / 2; ++mp) {
        const float4 q = sc4[mp];                    // one b128: 2 candidates
        const v2f X = {q.x, q.y};                    // (x0, x1)
        const v2f Y = {q.z, q.w};                    // (y0, y1)
        const v2f nrm = __builtin_elementwise_fma(Y, Y, X * X);   // |t|^2 packed
        #pragma unroll
        for (int j = 0; j < P; ++j) {
            // d' = |t|^2 - 2 p.t, two candidates at once (2x v_pk_fma_f32).
            const v2f d = __builtin_elementwise_fma(
                Y, n2y[j], __builtin_elementwise_fma(X, n2x[j], nrm));
            // strict < keeps FIRST minimal index; even candidate checked first.
            if (d.x < bd[j]) { bd[j] = d.x; bm[j] = 2 * mp; }
            if (d.y < bd[j]) { bd[j] = d.y; bm[j] = 2 * mp + 1; }
        }
    }

    // L1 contribution vs winning candidate (gather once per point).
    float c0 = 1.0f, c1 = 1.0f;
    if (dir == 0) { c0 = subcoef[0]; c1 = subcoef[1]; }
    float acc = 0.0f;
    #pragma unroll
    for (int j = 0; j < P; ++j) {
        const int g = bm[j] >> 1, o = bm[j] & 1;
        const float qx = sc[g * 4 + o];
        const float qy = sc[g * 4 + 2 + o];
        acc += fabsf(px[j] - qx) * c0 + fabsf(py[j] - qy) * c1;
    }

    // Wave (64) shuffle reduction -> block reduction -> one atomic per block.
    #pragma unroll
    for (int off = 32; off > 0; off >>= 1) acc += __shfl_down(acc, off, 64);
    if ((tid & 63) == 0) wsum[tid >> 6] = acc;
    __syncthreads();
    if (tid == 0) {
        float s = 0.0f;
        #pragma unroll
        for (int w = 0; w < BLOCK / 64; ++w) s += wsum[w];
        atomicAdd(out, s);
    }
}

extern "C" void kernel_launch(void* const* d_in, const int* in_sizes, int n_in,
                              void* d_out, int out_size, void* d_ws, size_t ws_size,
                              hipStream_t stream) {
    const float* preds   = (const float*)d_in[0];
    const float* targs   = (const float*)d_in[1];
    const float* subcoef = (const float*)d_in[2];
    float* out = (float*)d_out;

    hipMemsetAsync(out, 0, sizeof(float), stream);

    // 4 x 64 x 2 = 512 blocks -> 2 blocks/CU -> 8 waves/CU (2 per SIMD).
    dim3 grid(N / (BLOCK * P), B, 2);
    nnloss_kernel<<<grid, BLOCK, 0, stream>>>(preds, targs, subcoef, out);
}